// Round 5
// baseline (378.430 us; speedup 1.0000x reference)
//
#include <hip/hip_runtime.h>

#define HH 160
#define WW 160
#define PLANE (HH*WW)
#define RB 8              // output rows per block
#define SR (RB + 10)      // staged rows = 18  (taps reach i-4 .. i+5)
#define NB (HH / RB)      // 20 row-bands

// input:  (8, 1, 9, 160, 160) f32   weight: (3, 3, 48, 3) f32   offset: (16, 3, 2) f32
// out:    (16, 48, 160, 160) f32
// out[ob, g*16+o, i, j] = sum_{kh,kw,c} bilin(inp[ob/2, g*3+c],
//     i + (kh-1)*(1+3/off[ob,g,0]), j + (kw-1)*(1+3/off[ob,g,1])) * W[kh,kw,g*16+o,c]
// Zero-padded bilinear. fy,fx = 1+3/off ∈ (2,4] since off ∈ [1,3), so taps reach ±4 px.

__global__ __launch_bounds__(256, 4) void dcn_kernel(
    const float* __restrict__ inp,
    const float* __restrict__ weight,
    const float* __restrict__ offset,
    float* __restrict__ out)
{
    __shared__ float s_in[3 * SR * WW];   // [c][SR][WW]  8640 floats, zero-padded rows
    __shared__ float s_w[3 * 9 * 16];     // [c][k][o]    432 floats

    const int tid  = threadIdx.x;
    const int band = blockIdx.x;          // 0..19
    const int bg   = blockIdx.y;          // ob*3 + g, 0..47
    const int ob   = bg / 3;
    const int g    = bg % 3;

    const float* ibase = inp + ((size_t)(ob >> 1) * 9 + (size_t)g * 3) * PLANE;

    // ---- stage weights: s_w[(c*9+k)*16+o] = weight[(k*48 + g*16 + o)*3 + c]
    for (int idx = tid; idx < 432; idx += 256) {
        const int o  = idx & 15;
        const int ck = idx >> 4;
        const int k  = ck % 9;
        const int c  = ck / 9;
        s_w[idx] = weight[(k * 48 + g * 16 + o) * 3 + c];
    }

    // ---- stage input band: rows [rbase, rbase+SR) for 3 channels, zero for OOB rows
    const int rbase = band * RB - 4;
    {
        float4* s4 = reinterpret_cast<float4*>(s_in);
        const int NQ = 3 * SR * (WW / 4);   // 2160 float4s
        for (int q = tid; q < NQ; q += 256) {
            const int xq   = q % (WW / 4);
            const int rs   = (q / (WW / 4)) % SR;
            const int c    = q / ((WW / 4) * SR);
            const int grow = rbase + rs;
            float4 v = make_float4(0.f, 0.f, 0.f, 0.f);
            if ((unsigned)grow < (unsigned)HH)
                v = *reinterpret_cast<const float4*>(ibase + (size_t)c * PLANE + grow * WW + xq * 4);
            s4[q] = v;
        }
    }
    __syncthreads();

    const float fy = 1.0f + 3.0f / offset[bg * 2 + 0];
    const float fx = 1.0f + 3.0f / offset[bg * 2 + 1];

    for (int q = 0; q < (RB * WW) / 256; ++q) {   // 5 pixels per thread
        const int px = q * 256 + tid;             // 0..1279, lanes consecutive in j
        const int il = px / WW;                   // local row 0..7
        const int j  = px - il * WW;
        const int i  = band * RB + il;

        // per-kw column offsets and x-weights (mask folded in)
        int xo0[3], xo1[3];
        float b0[3], b1[3];
#pragma unroll
        for (int t = 0; t < 3; ++t) {
            const float xxf = (float)j + (float)(t - 1) * fx;
            const float x0f = floorf(xxf);
            const float wx  = xxf - x0f;
            const int   x0  = (int)x0f;
            xo0[t] = min(max(x0, 0), WW - 1);
            xo1[t] = min(max(x0 + 1, 0), WW - 1);
            b0[t] = ((unsigned)x0       < (unsigned)WW) ? (1.0f - wx) : 0.0f;
            b1[t] = ((unsigned)(x0 + 1) < (unsigned)WW) ? wx          : 0.0f;
        }

        float acc[16];
#pragma unroll
        for (int o = 0; o < 16; ++o) acc[o] = 0.f;

#pragma unroll
        for (int kh = 0; kh < 3; ++kh) {
            const float yyf = (float)i + (float)(kh - 1) * fy;
            const float y0f = floorf(yyf);
            const float wy  = yyf - y0f;
            const int   ry0 = (int)y0f - rbase;   // 0..15 by construction, zero-pad rows handle y-OOB
            const float a0  = 1.0f - wy, a1 = wy;
#pragma unroll
            for (int kw = 0; kw < 3; ++kw) {
                const float w00 = a0 * b0[kw], w01 = a0 * b1[kw];
                const float w10 = a1 * b0[kw], w11 = a1 * b1[kw];
                const int   k   = kh * 3 + kw;
#pragma unroll
                for (int c = 0; c < 3; ++c) {
                    const float* rp = &s_in[(c * SR + ry0) * WW];
                    const float v00 = rp[xo0[kw]];
                    const float v01 = rp[xo1[kw]];
                    const float v10 = rp[WW + xo0[kw]];
                    const float v11 = rp[WW + xo1[kw]];
                    const float s = fmaf(v11, w11, fmaf(v10, w10, fmaf(v01, w01, v00 * w00)));
                    const float* wp = &s_w[(c * 9 + k) * 16];
#pragma unroll
                    for (int o = 0; o < 16; ++o) acc[o] = fmaf(s, wp[o], acc[o]);
                }
            }
        }

        float* obase = out + ((size_t)ob * 48 + (size_t)g * 16) * PLANE + (size_t)i * WW + j;
#pragma unroll
        for (int o = 0; o < 16; ++o) obase[o * PLANE] = acc[o];
    }
}

extern "C" void kernel_launch(void* const* d_in, const int* in_sizes, int n_in,
                              void* d_out, int out_size, void* d_ws, size_t ws_size,
                              hipStream_t stream) {
    const float* inp    = (const float*)d_in[0];
    const float* weight = (const float*)d_in[1];
    const float* offset = (const float*)d_in[2];
    float* out = (float*)d_out;

    dim3 grid(NB, 16 * 3, 1);   // 20 x 48 = 960 blocks
    dim3 block(256, 1, 1);
    dcn_kernel<<<grid, block, 0, stream>>>(inp, weight, offset, out);
}

// Round 14
// 163.328 us; speedup vs baseline: 2.3170x; 2.3170x over previous
//
#include <hip/hip_runtime.h>

#define HH 160
#define WW 160
#define PLANE (HH*WW)
#define RB 8              // output rows per block
#define SR 17             // staged rows: taps reach floor(i-4)..floor(i+4)+1 = 17 rows
#define NB (HH / RB)      // 20 row-bands

// input:  (8, 1, 9, 160, 160) f32   weight: (3, 3, 48, 3) f32   offset: (16, 3, 2) f32
// out:    (16, 48, 160, 160) f32
// out[ob, g*16+o, i, j] = sum_{kh,kw,c} bilin(inp[ob/2, g*3+c],
//     i + (kh-1)*(1+3/off[ob,g,0]), j + (kw-1)*(1+3/off[ob,g,1])) * W[kh,kw,g*16+o,c]
// Zero-padded bilinear. fy,fx = 1+3/off ∈ (2,4], so taps reach at most ±4 px.

__global__ __launch_bounds__(256) void dcn_kernel(
    const float* __restrict__ inp,
    const float* __restrict__ weight,
    const float* __restrict__ offset,
    float* __restrict__ out)
{
    __shared__ __align__(16) float s_in[3 * SR * WW];   // [c][SR][WW], zero-padded OOB rows
    __shared__ __align__(16) float s_w[3 * 9 * 16];     // [c][k][o]

    const int tid  = threadIdx.x;
    const int band = blockIdx.x;          // 0..19
    const int bg   = blockIdx.y;          // ob*3 + g, 0..47
    const int ob   = bg / 3;
    const int g    = bg % 3;

    const float* ibase = inp + ((size_t)(ob >> 1) * 9 + (size_t)g * 3) * PLANE;

    // ---- stage weights: s_w[(c*9+k)*16+o] = weight[(k*48 + g*16 + o)*3 + c]
    for (int idx = tid; idx < 432; idx += 256) {
        const int o  = idx & 15;
        const int ck = idx >> 4;
        const int k  = ck % 9;
        const int c  = ck / 9;
        s_w[idx] = weight[(k * 48 + g * 16 + o) * 3 + c];
    }

    // ---- stage input band: rows [rbase, rbase+SR), 3 channels, zeros for OOB rows
    const int rbase = band * RB - 4;
    {
        float4* s4 = reinterpret_cast<float4*>(s_in);
        const int NQ = 3 * SR * (WW / 4);   // 2040 float4s
        for (int q = tid; q < NQ; q += 256) {
            const int xq   = q % (WW / 4);
            const int rs   = (q / (WW / 4)) % SR;
            const int c    = q / ((WW / 4) * SR);
            const int grow = rbase + rs;
            float4 v = make_float4(0.f, 0.f, 0.f, 0.f);
            if ((unsigned)grow < (unsigned)HH)
                v = *reinterpret_cast<const float4*>(ibase + (size_t)c * PLANE + grow * WW + xq * 4);
            s4[q] = v;
        }
    }
    __syncthreads();

    const float fy = 1.0f + 3.0f / offset[bg * 2 + 0];
    const float fx = 1.0f + 3.0f / offset[bg * 2 + 1];

#pragma unroll 1
    for (int q = 0; q < (RB * WW) / 256; ++q) {   // 5 pixel-groups per thread, NO unroll (spill guard)
        const int px = q * 256 + tid;             // lanes consecutive in memory
        const int il = px / WW;
        const int j  = px - il * WW;
        const int i  = band * RB + il;

        // per-kw column offsets and x-weights (OOB mask folded into weights)
        int xo0[3], xo1[3];
        float b0[3], b1[3];
#pragma unroll
        for (int t = 0; t < 3; ++t) {
            const float xxf = (float)j + (float)(t - 1) * fx;
            const float x0f = floorf(xxf);
            const float wx  = xxf - x0f;
            const int   x0  = (int)x0f;
            xo0[t] = min(max(x0, 0), WW - 1);
            xo1[t] = min(max(x0 + 1, 0), WW - 1);
            b0[t] = ((unsigned)x0       < (unsigned)WW) ? (1.0f - wx) : 0.0f;
            b1[t] = ((unsigned)(x0 + 1) < (unsigned)WW) ? wx          : 0.0f;
        }

        float acc[16];
#pragma unroll
        for (int o = 0; o < 16; ++o) acc[o] = 0.f;

#pragma unroll
        for (int kh = 0; kh < 3; ++kh) {
            const float yyf = (float)i + (float)(kh - 1) * fy;
            const float y0f = floorf(yyf);
            const float wy  = yyf - y0f;
            const int   ry0 = (int)y0f - rbase;   // 0..15 by construction
            const float a0  = 1.0f - wy, a1 = wy;
#pragma unroll
            for (int kw = 0; kw < 3; ++kw) {
                const float w00 = a0 * b0[kw], w01 = a0 * b1[kw];
                const float w10 = a1 * b0[kw], w11 = a1 * b1[kw];
                const int   k   = kh * 3 + kw;
#pragma unroll
                for (int c = 0; c < 3; ++c) {
                    const float* rp = &s_in[(c * SR + ry0) * WW];
                    const float v00 = rp[xo0[kw]];
                    const float v01 = rp[xo1[kw]];
                    const float v10 = rp[WW + xo0[kw]];
                    const float v11 = rp[WW + xo1[kw]];
                    const float s = fmaf(v11, w11, fmaf(v10, w10, fmaf(v01, w01, v00 * w00)));
                    // broadcast (wave-uniform address) float4 weight reads: 4x ds_read_b128
                    const float4* wp4 = reinterpret_cast<const float4*>(&s_w[(c * 9 + k) * 16]);
                    const float4 wa = wp4[0], wb = wp4[1], wc = wp4[2], wd = wp4[3];
                    acc[ 0] = fmaf(s, wa.x, acc[ 0]);  acc[ 1] = fmaf(s, wa.y, acc[ 1]);
                    acc[ 2] = fmaf(s, wa.z, acc[ 2]);  acc[ 3] = fmaf(s, wa.w, acc[ 3]);
                    acc[ 4] = fmaf(s, wb.x, acc[ 4]);  acc[ 5] = fmaf(s, wb.y, acc[ 5]);
                    acc[ 6] = fmaf(s, wb.z, acc[ 6]);  acc[ 7] = fmaf(s, wb.w, acc[ 7]);
                    acc[ 8] = fmaf(s, wc.x, acc[ 8]);  acc[ 9] = fmaf(s, wc.y, acc[ 9]);
                    acc[10] = fmaf(s, wc.z, acc[10]);  acc[11] = fmaf(s, wc.w, acc[11]);
                    acc[12] = fmaf(s, wd.x, acc[12]);  acc[13] = fmaf(s, wd.y, acc[13]);
                    acc[14] = fmaf(s, wd.z, acc[14]);  acc[15] = fmaf(s, wd.w, acc[15]);
                }
            }
        }

        float* obase = out + ((size_t)ob * 48 + (size_t)g * 16) * PLANE + (size_t)i * WW + j;
#pragma unroll
        for (int o = 0; o < 16; ++o) obase[o * PLANE] = acc[o];
    }
}

extern "C" void kernel_launch(void* const* d_in, const int* in_sizes, int n_in,
                              void* d_out, int out_size, void* d_ws, size_t ws_size,
                              hipStream_t stream) {
    const float* inp    = (const float*)d_in[0];
    const float* weight = (const float*)d_in[1];
    const float* offset = (const float*)d_in[2];
    float* out = (float*)d_out;

    dim3 grid(NB, 16 * 3, 1);   // 20 x 48 = 960 blocks
    dim3 block(256, 1, 1);
    dcn_kernel<<<grid, block, 0, stream>>>(inp, weight, offset, out);
}

// Round 15
// 107.515 us; speedup vs baseline: 3.5198x; 1.5191x over previous
//
#include <hip/hip_runtime.h>

#define HH 160
#define WW 160
#define PLANE (HH*WW)
#define RB 8              // output rows per block
#define SR 17             // staged rows (taps reach i-4 .. i+5)
#define NB (HH / RB)      // 20 row-bands
#define PADW 172          // 4 zero cols left + 160 data + 8 zero cols right
#define LPAD 4

// input:  (8, 1, 9, 160, 160) f32   weight: (3, 3, 48, 3) f32   offset: (16, 3, 2) f32
// out:    (16, 48, 160, 160) f32
//
// Offsets are uniform per (ob,g): tap displacement dy=(kh-1)*fy has CONSTANT
// integer part Dy and fraction wy per block. Sampling = 4 reads at fixed
// offsets + 3 lerps; OOB handled by zero-padded LDS (rows and columns).
// Contraction over k'=(tap,c), K=27<=32 -> one mfma_f32_16x16x32_bf16 per
// 16-pixel tile; weight B-fragment lives in 4 VGPRs for the whole block.

typedef __attribute__((ext_vector_type(8))) short bf16x8;
typedef __attribute__((ext_vector_type(4))) float f32x4;

__device__ __forceinline__ short f2bf(float f) {
    union { float f; unsigned u; } v; v.f = f;
    const unsigned r = v.u + 0x7fffu + ((v.u >> 16) & 1u);   // RNE, finite inputs
    return (short)(r >> 16);
}

__global__ __launch_bounds__(256) void dcn_mfma(
    const float* __restrict__ inp,
    const float* __restrict__ weight,
    const float* __restrict__ offset,
    float* __restrict__ out)
{
    __shared__ __align__(16) float s_in[3 * SR * PADW];   // [c][SR][PADW], zero-padded

    const int tid  = threadIdx.x;
    const int band = blockIdx.x;          // 0..19
    const int bg   = blockIdx.y;          // ob*3 + g
    const int ob   = bg / 3;
    const int g    = bg % 3;

    const float* ibase = inp + ((size_t)(ob >> 1) * 9 + (size_t)g * 3) * PLANE;
    const int rbase = band * RB - 4;

    // ---- stage band into padded LDS (float4 rows are 16B-aligned: PADW*4=688) ----
    {
        float4* s4 = reinterpret_cast<float4*>(s_in);
        for (int q = tid; q < 3 * SR * 40; q += 256) {        // data cols 4..163
            const int xq = q % 40;
            const int rs = (q / 40) % SR;
            const int c  = q / (40 * SR);
            const int grow = rbase + rs;
            float4 v = make_float4(0.f, 0.f, 0.f, 0.f);
            if ((unsigned)grow < (unsigned)HH)
                v = *reinterpret_cast<const float4*>(ibase + (size_t)c * PLANE + grow * WW + xq * 4);
            s4[(c * SR + rs) * 43 + 1 + xq] = v;
        }
        const float4 z = make_float4(0.f, 0.f, 0.f, 0.f);     // pad cols 0..3, 164..171
        for (int p = tid; p < 3 * SR * 3; p += 256) {
            const int pi = p % 3;
            const int rs = (p / 3) % SR;
            const int c  = p / (3 * SR);
            s4[(c * SR + rs) * 43 + (pi == 0 ? 0 : 40 + pi)] = z;
        }
    }

    const float fy = 1.0f + 3.0f / offset[bg * 2 + 0];
    const float fx = 1.0f + 3.0f / offset[bg * 2 + 1];

    const int lane = tid & 63;
    const int wid  = tid >> 6;
    const int l15  = lane & 15;       // A-row pixel / B-col output / store channel
    const int kgrp = lane >> 4;       // k-slot group

    // ---- per-lane constants + B-fragment (weights, once per block) ----
    bf16x8 bfrag;
    float wyv[8], wxv[8];
    int   dlt[8];
#pragma unroll
    for (int m = 0; m < 8; ++m) {
        const int kp = kgrp * 8 + m;                          // k' slot
        if (kp < 27) {
            const int tap = kp / 3;
            const int c   = kp - 3 * tap;
            const int kh  = tap / 3;
            const int kw  = tap - 3 * kh;
            const float dy = (float)(kh - 1) * fy;
            const float dx = (float)(kw - 1) * fx;
            const float Dyf = floorf(dy), Dxf = floorf(dx);
            wyv[m] = dy - Dyf;                                // constant fractions
            wxv[m] = dx - Dxf;
            dlt[m] = (c * SR + (int)Dyf) * PADW + (int)Dxf;   // float-index delta
            bfrag[m] = f2bf(weight[(tap * 48 + g * 16 + l15) * 3 + c]);
        } else {                                              // K-pad 27..31
            wyv[m] = 0.f; wxv[m] = 0.f; dlt[m] = 0; bfrag[m] = 0;
        }
    }
    __syncthreads();

    // ---- 80 tiles (8 rows x 10 tiles of 16 px), 20 per wave ----
    for (int t = wid; t < RB * 10; t += 4) {
        const int il = t / 10;
        const int jt = (t % 10) * 16;
        const int i  = band * RB + il;
        const int base = (il + 4) * PADW + LPAD + jt + l15;   // this lane's pixel

        bf16x8 afrag;
#pragma unroll
        for (int m = 0; m < 8; ++m) {
            const float* p = s_in + base + dlt[m];
            const float v00 = p[0],    v01 = p[1];
            const float v10 = p[PADW], v11 = p[PADW + 1];
            const float r0 = v00 + wyv[m] * (v10 - v00);      // y-lerp
            const float r1 = v01 + wyv[m] * (v11 - v01);
            const float s  = r0 + wxv[m] * (r1 - r0);         // x-lerp
            afrag[m] = f2bf(s);
        }

        f32x4 acc = {0.f, 0.f, 0.f, 0.f};
        acc = __builtin_amdgcn_mfma_f32_16x16x32_bf16(afrag, bfrag, acc, 0, 0, 0);

        // C/D: col=lane&15 (=o), row=(lane>>4)*4+reg (=pixel) -> float4 store
        float* op = out + ((size_t)ob * 48 + g * 16 + l15) * PLANE
                        + (size_t)i * WW + jt + kgrp * 4;
        *reinterpret_cast<f32x4*>(op) = acc;
    }
}

extern "C" void kernel_launch(void* const* d_in, const int* in_sizes, int n_in,
                              void* d_out, int out_size, void* d_ws, size_t ws_size,
                              hipStream_t stream) {
    const float* inp    = (const float*)d_in[0];
    const float* weight = (const float*)d_in[1];
    const float* offset = (const float*)d_in[2];
    float* out = (float*)d_out;

    dim3 grid(NB, 16 * 3, 1);   // 20 x 48 = 960 blocks
    dim3 block(256, 1, 1);
    dcn_mfma<<<grid, block, 0, stream>>>(inp, weight, offset, out);
}